// Round 14
// baseline (88.305 us; speedup 1.0000x reference)
//
#include <hip/hip_runtime.h>
#include <hip/hip_bf16.h>

typedef short s4 __attribute__((ext_vector_type(4)));
typedef short s8 __attribute__((ext_vector_type(8)));
typedef float f4 __attribute__((ext_vector_type(4)));
typedef float f16v __attribute__((ext_vector_type(16)));

#define MFMA16(a, b, c) __builtin_amdgcn_mfma_f32_16x16x16bf16_1k(a, b, c, 0, 0, 0)
#define MFMA32(a, b, c) __builtin_amdgcn_mfma_f32_32x32x8bf16_1k(a, b, c, 0, 0, 0)

__device__ __forceinline__ short f2bf(float f) {
    union { float f; unsigned u; } v; v.f = f;
    unsigned r = v.u + 0x7fffu + ((v.u >> 16) & 1u);   // RNE
    return (short)(r >> 16);
}

// ---------------------------------------------------------------------------
// Kernel 0: W fp32 [1024][64] -> bf16 row-major copy (halves proj W traffic).
// ---------------------------------------------------------------------------
struct WcArgs { const float* W[3]; unsigned short* O; };

__global__ __launch_bounds__(256) void wconv_kernel(WcArgs a) {
    const int which = blockIdx.y;
    const int id = blockIdx.x * 256 + threadIdx.x;     // f4 index 0..16383
    f4 w = *(const f4*)(a.W[which] + (size_t)id * 4);
    s4 o; o[0]=f2bf(w[0]); o[1]=f2bf(w[1]); o[2]=f2bf(w[2]); o[3]=f2bf(w[3]);
    *(s4*)(a.O + (size_t)which * 65536 + (size_t)id * 4) = o;
}

// ---------------------------------------------------------------------------
// Kernel 1: projections — R8 structure, W staged from bf16 copy.
// V (which==2) stored as transposed 64-key tiles vpT[b][tile][d][key].
// ---------------------------------------------------------------------------
struct ProjArgs {
    const float* X[3];
    const float* b[3];
    const unsigned short* Wbf;
    unsigned short* O[3];
};

__global__ __launch_bounds__(256) void proj_kernel(ProjArgs args) {
    __shared__ short lA[64][68];   // [row][k]
    __shared__ short lW[64][72];   // [k][n]

    const int t  = threadIdx.x;
    const int wv = t >> 6, ln = t & 63, lg = ln >> 4, lr = ln & 15;
    const int which = blockIdx.y;

    const float* X = args.X[which] + (size_t)blockIdx.x * 64 * 1024;
    const unsigned short* Wb = args.Wbf + (size_t)which * 65536;

    f4 acc[4] = {f4{0,0,0,0}, f4{0,0,0,0}, f4{0,0,0,0}, f4{0,0,0,0}};

    for (int kk = 0; kk < 1024; kk += 64) {
        #pragma unroll
        for (int i = 0; i < 4; ++i) {
            int f  = t + i * 256;       // float4 index, 0..1023
            int r  = f >> 4;
            int c4 = f & 15;
            f4 a = *(const f4*)(X + (size_t)r * 1024 + kk + c4 * 4);
            s4 ab; ab[0]=f2bf(a[0]); ab[1]=f2bf(a[1]); ab[2]=f2bf(a[2]); ab[3]=f2bf(a[3]);
            *(s4*)&lA[r][c4 * 4] = ab;
        }
        #pragma unroll
        for (int i = 0; i < 2; ++i) {
            int s = t + i * 256;        // s8 index, 0..511
            int r = s >> 3, c8 = s & 7;
            s8 w8 = *(const s8*)(Wb + (size_t)(kk + r) * 64 + c8 * 8);
            *(s8*)&lW[r][c8 * 8] = w8;
        }
        __syncthreads();

        #pragma unroll
        for (int ks = 0; ks < 4; ++ks) {
            s4 af = *(const s4*)&lA[wv * 16 + lr][ks * 16 + 4 * lg];
            #pragma unroll
            for (int nf = 0; nf < 4; ++nf) {
                s4 bf;
                #pragma unroll
                for (int e = 0; e < 4; ++e)
                    bf[e] = lW[ks * 16 + 4 * lg + e][nf * 16 + lr];
                acc[nf] = MFMA16(af, bf, acc[nf]);
            }
        }
        __syncthreads();
    }

    const float* bias = args.b[which];
    unsigned short* O = args.O[which];
    #pragma unroll
    for (int nf = 0; nf < 4; ++nf) {
        float bs = bias[nf * 16 + lr];
        int col = nf * 16 + lr;
        #pragma unroll
        for (int e = 0; e < 4; ++e) {
            int r = wv * 16 + 4 * lg + e;
            int grow = blockIdx.x * 64 + r;
            unsigned short val = (unsigned short)f2bf(acc[nf][e] + bs);
            if (which == 2) {
                size_t idx = (size_t)(grow >> 11) * 131072
                           + (size_t)((grow & 2047) >> 6) * 4096
                           + (size_t)col * 64 + (grow & 63);
                O[idx] = val;
            } else {
                O[(size_t)grow * 64 + col] = val;
            }
        }
    }
}

// ---------------------------------------------------------------------------
// Kernel 2 v13b: causal flash attention on 32x32x8 MFMA.
// FIX vs v13: PV key-slice loop is ks in [0,4) (32-key sub = 4 K=8 slices);
// v13's ks<8 indexed st[s][16..35] out of the 16-wide accumulator (UB->NaN)
// and read lV past the tile. QK keeps ks<8 (d=64 = 8 K=8 slices).
// q-tile = 128 rows; 8 waves = 4 q-cols x 2 kv-halves; z = 2 chunks.
// grid (32, 8), big q-tiles first. Partials -> ws; attn_merge combines.
// ---------------------------------------------------------------------------
__global__ __launch_bounds__(512) void attn_part(const unsigned short* __restrict__ qp,
                                                 const unsigned short* __restrict__ kp,
                                                 const unsigned short* __restrict__ vpT,
                                                 float* __restrict__ partO,
                                                 float* __restrict__ partML) {
    __shared__ short lK[2][2][64][76];   // [half][buf][key][d]
    __shared__ short lV[2][2][64][76];   // [half][buf][d][key]

    const int t = threadIdx.x;
    const int wave = t >> 6, l = t & 63, lq = l & 31, h = l >> 5;
    const int qcol = wave >> 1, half = wave & 1;
    const int b = blockIdx.y, x = blockIdx.x;
    const int g = 15 - (x >> 1), z = x & 1;           // big q-tiles first
    const int cnt = g + 1;                            // tiles per chunk (total 2(g+1))
    const int base = z * cnt, hA = (cnt + 1) >> 1;
    const int qg = 128 * g + 32 * qcol + lq;          // this lane's q row
    const int qmaxw = 128 * g + 32 * qcol + 31;
    const int qminw = 128 * g + 32 * qcol;

    // staging role: 128-thr groups: 0=K halfA, 1=V halfA, 2=K halfB, 3=V halfB
    const int sg = t >> 7, gi = t & 127, sHalf = sg >> 1;
    const bool sIsV = (sg & 1) != 0;
    const unsigned short* tb = (sIsV ? vpT : kp) + (size_t)b * 131072;

    const unsigned short* qpb = qp + (size_t)b * 131072;
    s4 qf[8];
    #pragma unroll
    for (int ks = 0; ks < 8; ++ks)
        qf[ks] = *(const s4*)(qpb + (size_t)qg * 64 + ks * 8 + 4 * h);

    f16v accO[2];
    #pragma unroll
    for (int df = 0; df < 2; ++df)
        #pragma unroll
        for (int r = 0; r < 16; ++r) accO[df][r] = 0.f;
    float m = -3e38f, lsum = 0.f;

    // prologue prefetch
    s8 stg[4];
    {
        int tile = base + (sHalf ? hA : 0); if (tile > 31) tile = 31;
        const unsigned short* p = tb + (size_t)tile * 4096;
        #pragma unroll
        for (int i = 0; i < 4; ++i)
            stg[i] = *(const s8*)(p + (gi + 128 * i) * 8);
    }

    int buf = 0;
    for (int j = 0; j < hA; ++j) {
        {
            short (*dst)[76] = sIsV ? lV[sHalf][buf] : lK[sHalf][buf];
            #pragma unroll
            for (int i = 0; i < 4; ++i) {
                int s = gi + 128 * i;
                s4 lo = __builtin_shufflevector(stg[i], stg[i], 0, 1, 2, 3);
                s4 hi = __builtin_shufflevector(stg[i], stg[i], 4, 5, 6, 7);
                *(s4*)&dst[s >> 3][(s & 7) * 8] = lo;
                *(s4*)&dst[s >> 3][(s & 7) * 8 + 4] = hi;
            }
        }
        __syncthreads();

        if (j + 1 < hA) {
            int tile = base + (sHalf ? hA : 0) + j + 1; if (tile > 31) tile = 31;
            const unsigned short* p = tb + (size_t)tile * 4096;
            #pragma unroll
            for (int i = 0; i < 4; ++i)
                stg[i] = *(const s8*)(p + (gi + 128 * i) * 8);
        }

        const int kt = base + (half ? hA : 0) + j;
        const int kbase = kt * 64;
        if (kt < base + cnt && kbase <= qmaxw) {
            // S^T = K . Q^T  (two 32-key subs x 32 q), d-contraction: 8 K=8 slices
            f16v st[2];
            #pragma unroll
            for (int s = 0; s < 2; ++s)
                #pragma unroll
                for (int r = 0; r < 16; ++r) st[s][r] = 0.f;
            #pragma unroll
            for (int ks = 0; ks < 8; ++ks) {
                s4 k0 = *(const s4*)&lK[half][buf][lq][ks * 8 + 4 * h];
                s4 k1 = *(const s4*)&lK[half][buf][32 + lq][ks * 8 + 4 * h];
                st[0] = MFMA32(k0, qf[ks], st[0]);
                st[1] = MFMA32(k1, qf[ks], st[1]);
            }

            // scale + causal mask + row max (one shfl: partner lane l^32)
            const bool needMask = (kbase + 63 > qminw);
            float smax = -3e38f;
            #pragma unroll
            for (int s = 0; s < 2; ++s)
                #pragma unroll
                for (int r = 0; r < 16; ++r) {
                    int key = kbase + s * 32 + 8 * (r >> 2) + 4 * h + (r & 3);
                    float val = st[s][r] * 0.125f;
                    if (needMask && key > qg) val = -3e38f;
                    st[s][r] = val;
                    smax = fmaxf(smax, val);
                }
            smax = fmaxf(smax, __shfl_xor(smax, 32));

            float mnew  = fmaxf(m, smax);
            float scale = __expf(m - mnew);
            lsum *= scale;
            m = mnew;
            #pragma unroll
            for (int df = 0; df < 2; ++df)
                #pragma unroll
                for (int r = 0; r < 16; ++r) accO[df][r] *= scale;

            // P = exp(S - m); PV key-contraction: per sub s, 4 K=8 slices
            float psum = 0.f;
            #pragma unroll
            for (int s = 0; s < 2; ++s) {
                s4 pf[4];
                #pragma unroll
                for (int ks = 0; ks < 4; ++ks) {
                    f4 p;
                    #pragma unroll
                    for (int e = 0; e < 4; ++e)
                        p[e] = __expf(st[s][4 * ks + e] - mnew);
                    psum += (p[0] + p[1]) + (p[2] + p[3]);
                    s4 pc; pc[0]=f2bf(p[0]); pc[1]=f2bf(p[1]); pc[2]=f2bf(p[2]); pc[3]=f2bf(p[3]);
                    pf[ks] = pc;
                }
                #pragma unroll
                for (int df = 0; df < 2; ++df)
                    #pragma unroll
                    for (int ks = 0; ks < 4; ++ks) {
                        s4 vf = *(const s4*)&lV[half][buf][32 * df + lq]
                                               [s * 32 + ks * 8 + 4 * h];
                        accO[df] = MFMA32(vf, pf[ks], accO[df]);
                    }
            }
            psum += __shfl_xor(psum, 32);
            lsum += psum;
        }
        buf ^= 1;
    }

    // ---- merge halves (per qcol), write unnormalized partial ----
    __syncthreads();
    float* ex = (float*)&lK[0][0][0][0];     // 4*64*34 = 8704 floats (34.8 KB)
    const int idx = (qcol * 64 + l) * 34;
    if (half == 1) {
        ex[idx + 0] = m;
        ex[idx + 1] = lsum;
        #pragma unroll
        for (int df = 0; df < 2; ++df)
            #pragma unroll
            for (int r = 0; r < 16; ++r)
                ex[idx + 2 + df * 16 + r] = accO[df][r];
    }
    __syncthreads();
    if (half == 0) {
        float mB = ex[idx + 0], lB = ex[idx + 1];
        float mx = fmaxf(m, mB);
        float sA = __expf(m - mx), sB = __expf(mB - mx);
        float lP = lsum * sA + lB * sB;

        const size_t pidx = ((size_t)(b * 16 + g)) * 2 + z;
        float* Od = partO + pidx * 8192 + (size_t)(32 * qcol + lq) * 64;
        #pragma unroll
        for (int df = 0; df < 2; ++df)
            #pragma unroll
            for (int rg = 0; rg < 4; ++rg) {
                f4 o;
                #pragma unroll
                for (int e = 0; e < 4; ++e)
                    o[e] = accO[df][4 * rg + e] * sA
                         + ex[idx + 2 + df * 16 + 4 * rg + e] * sB;
                *(f4*)(Od + 32 * df + 8 * rg + 4 * h) = o;
            }
        if (h == 0) {
            partML[pidx * 256 + (32 * qcol + lq) * 2 + 0] = mx;
            partML[pidx * 256 + (32 * qcol + lq) * 2 + 1] = lP;
        }
    }
}

// ---------------------------------------------------------------------------
// Kernel 3: merge the two z-chunk partials. grid (16, 8), 256 thr.
// ---------------------------------------------------------------------------
__global__ __launch_bounds__(256) void attn_merge(const float* __restrict__ partO,
                                                  const float* __restrict__ partML,
                                                  float* __restrict__ out) {
    const int t = threadIdx.x;
    const int gg = blockIdx.x, b = blockIdx.y;
    const int q = t >> 1, dh = t & 1;

    const size_t p0 = ((size_t)(b * 16 + gg)) * 2;
    const size_t p1 = p0 + 1;
    float m0 = partML[p0 * 256 + q * 2], l0 = partML[p0 * 256 + q * 2 + 1];
    float m1 = partML[p1 * 256 + q * 2], l1 = partML[p1 * 256 + q * 2 + 1];
    float M  = fmaxf(m0, m1);
    float s0 = __expf(m0 - M), s1 = __expf(m1 - M);
    float inv = 1.f / (l0 * s0 + l1 * s1);

    const float* O0 = partO + p0 * 8192 + (size_t)q * 64 + dh * 32;
    const float* O1 = partO + p1 * 8192 + (size_t)q * 64 + dh * 32;
    float* ob = out + ((size_t)b * 2048 + gg * 128 + q) * 64 + dh * 32;
    #pragma unroll
    for (int i = 0; i < 8; ++i) {
        f4 a = *(const f4*)(O0 + 4 * i);
        f4 c = *(const f4*)(O1 + 4 * i);
        f4 o;
        #pragma unroll
        for (int e = 0; e < 4; ++e) o[e] = (a[e] * s0 + c[e] * s1) * inv;
        *(f4*)(ob + 4 * i) = o;
    }
}

// ---------------------------------------------------------------------------
extern "C" void kernel_launch(void* const* d_in, const int* in_sizes, int n_in,
                              void* d_out, int out_size, void* d_ws, size_t ws_size,
                              hipStream_t stream) {
    const float* q  = (const float*)d_in[0];
    const float* k  = (const float*)d_in[1];
    const float* v  = (const float*)d_in[2];
    // d_in[3] = causal mask (deterministic tril) — computed analytically
    const float* Wq = (const float*)d_in[4];
    const float* bq = (const float*)d_in[5];
    const float* Wk = (const float*)d_in[6];
    const float* bk = (const float*)d_in[7];
    const float* Wv = (const float*)d_in[8];
    const float* bv = (const float*)d_in[9];

    unsigned short* qp  = (unsigned short*)d_ws;           // [16384][64] bf16
    unsigned short* kp  = qp + (size_t)16384 * 64;
    unsigned short* vpT = kp + (size_t)16384 * 64;         // V^T tiles [b][t][d][key]
    unsigned short* wbf = vpT + (size_t)16384 * 64;        // 3x[1024][64] bf16 W
    float* partO  = (float*)(wbf + (size_t)3 * 65536);     // [256][128][64] f32 (8 MB)
    float* partML = partO + (size_t)256 * 8192;            // [256][128][2] f32

    WcArgs wa;
    wa.W[0] = Wq; wa.W[1] = Wk; wa.W[2] = Wv;
    wa.O = wbf;
    wconv_kernel<<<dim3(64, 3), 256, 0, stream>>>(wa);

    ProjArgs pa;
    pa.X[0] = q;  pa.X[1] = k;  pa.X[2] = v;
    pa.b[0] = bq; pa.b[1] = bk; pa.b[2] = bv;
    pa.Wbf = wbf;
    pa.O[0] = qp; pa.O[1] = kp; pa.O[2] = vpT;
    proj_kernel<<<dim3(256, 3), 256, 0, stream>>>(pa);

    attn_part<<<dim3(32, 8), 512, 0, stream>>>(qp, kp, vpT, partO, partML);
    attn_merge<<<dim3(16, 8), 256, 0, stream>>>(partO, partML, (float*)d_out);
}

// Round 15
// 77.173 us; speedup vs baseline: 1.1443x; 1.1443x over previous
//
#include <hip/hip_runtime.h>
#include <hip/hip_bf16.h>

typedef short s4 __attribute__((ext_vector_type(4)));
typedef short s8 __attribute__((ext_vector_type(8)));
typedef float f4 __attribute__((ext_vector_type(4)));

#define MFMA16(a, b, c) __builtin_amdgcn_mfma_f32_16x16x16bf16_1k(a, b, c, 0, 0, 0)

__device__ __forceinline__ short f2bf(float f) {
    union { float f; unsigned u; } v; v.f = f;
    unsigned r = v.u + 0x7fffu + ((v.u >> 16) & 1u);   // RNE
    return (short)(r >> 16);
}

// ---------------------------------------------------------------------------
// Kernel 1: projections — R8 exact (best timed performer: ~47.5 us warm;
// cold rocprof ~86 us is the serialized-cold regime, not what is timed).
// 64x64 tile, merged X+W LDS staging (8 loads in flight), 4 waves.
// V (which==2) stored as transposed 64-key tiles vpT[b][tile][d][key].
// ---------------------------------------------------------------------------
struct ProjArgs {
    const float* X[3];
    const float* W[3];
    const float* b[3];
    unsigned short* O[3];
};

__global__ __launch_bounds__(256) void proj_kernel(ProjArgs args) {
    __shared__ short lA[64][68];   // [row][k]
    __shared__ short lW[64][68];   // [k][n]

    const int t  = threadIdx.x;
    const int wv = t >> 6, ln = t & 63, lg = ln >> 4, lr = ln & 15;
    const int which = blockIdx.y;

    const float* X = args.X[which] + (size_t)blockIdx.x * 64 * 1024;
    const float* W = args.W[which];

    f4 acc[4] = {f4{0,0,0,0}, f4{0,0,0,0}, f4{0,0,0,0}, f4{0,0,0,0}};

    for (int kk = 0; kk < 1024; kk += 64) {
        #pragma unroll
        for (int i = 0; i < 4; ++i) {
            int f  = t + i * 256;       // float4 index, 0..1023
            int r  = f >> 4;
            int c4 = f & 15;
            f4 a = *(const f4*)(X + (size_t)r * 1024 + kk + c4 * 4);
            f4 w = *(const f4*)(W + (size_t)(kk + r) * 64 + c4 * 4);
            s4 ab; ab[0]=f2bf(a[0]); ab[1]=f2bf(a[1]); ab[2]=f2bf(a[2]); ab[3]=f2bf(a[3]);
            s4 wb; wb[0]=f2bf(w[0]); wb[1]=f2bf(w[1]); wb[2]=f2bf(w[2]); wb[3]=f2bf(w[3]);
            *(s4*)&lA[r][c4 * 4] = ab;
            *(s4*)&lW[r][c4 * 4] = wb;
        }
        __syncthreads();

        #pragma unroll
        for (int ks = 0; ks < 4; ++ks) {
            s4 af = *(const s4*)&lA[wv * 16 + lr][ks * 16 + 4 * lg];
            #pragma unroll
            for (int nf = 0; nf < 4; ++nf) {
                s4 bf;
                #pragma unroll
                for (int e = 0; e < 4; ++e)
                    bf[e] = lW[ks * 16 + 4 * lg + e][nf * 16 + lr];
                acc[nf] = MFMA16(af, bf, acc[nf]);
            }
        }
        __syncthreads();
    }

    // epilogue: + bias, bf16, store (V transposed per 64-key tile)
    const float* bias = args.b[which];
    unsigned short* O = args.O[which];
    #pragma unroll
    for (int nf = 0; nf < 4; ++nf) {
        float bs = bias[nf * 16 + lr];
        int col = nf * 16 + lr;
        #pragma unroll
        for (int e = 0; e < 4; ++e) {
            int r = wv * 16 + 4 * lg + e;
            int grow = blockIdx.x * 64 + r;
            unsigned short val = (unsigned short)f2bf(acc[nf][e] + bs);
            if (which == 2) {
                size_t idx = (size_t)(grow >> 11) * 131072
                           + (size_t)((grow & 2047) >> 6) * 4096
                           + (size_t)col * 64 + (grow & 63);
                O[idx] = val;
            } else {
                O[(size_t)grow * 64 + col] = val;
            }
        }
    }
}

// ---------------------------------------------------------------------------
// Kernel 2: causal flash attention — R8 exact (best: ~28.7 us timed).
// Intra-block 2-way KV-split, 8 waves, double-buffered LDS, one barrier/iter,
// reg prefetch; V staged from vpT with vector s8 writes. grid (32,8), 512 thr.
// ---------------------------------------------------------------------------
__global__ __launch_bounds__(512) void attn_kernel(const unsigned short* __restrict__ qp,
                                                   const unsigned short* __restrict__ kp,
                                                   const unsigned short* __restrict__ vpT,
                                                   float* __restrict__ out) {
    __shared__ short lK[2][2][64][72];   // [half][buf][key][d]
    __shared__ short lV[2][2][64][72];   // [half][buf][d][key]

    const int t    = threadIdx.x;
    const int wave = t >> 6, ln = t & 63, lg = ln >> 4, lr = ln & 15;
    const int half = wave >> 2, hw = wave & 3;
    const int b = blockIdx.y, qt = blockIdx.x;
    const int qrow = qt * 64 + hw * 16 + lr;
    const int h = (qt + 2) >> 1;

    // staging role: 128-thread groups g: 0=K half0, 1=V half0, 2=K half1, 3=V half1
    const int g = t >> 7, gi = t & 127, ghalf = g >> 1;
    const bool isV = (g & 1) != 0;
    const unsigned short* tb = (isV ? vpT : kp) + (size_t)b * 131072;

    const unsigned short* qpb = qp + (size_t)b * 131072;
    s4 qf[4];
    #pragma unroll
    for (int ks = 0; ks < 4; ++ks)
        qf[ks] = *(const s4*)(qpb + (size_t)qrow * 64 + ks * 16 + 4 * lg);

    f4 accO[4] = {f4{0,0,0,0}, f4{0,0,0,0}, f4{0,0,0,0}, f4{0,0,0,0}};
    float m = -3e38f, lsum = 0.f;

    // prologue: prefetch iter-0 tile for this thread's (tensor, half)
    s8 stg[4];
    {
        const unsigned short* p = tb + (size_t)(ghalf ? h : 0) * 4096;
        #pragma unroll
        for (int i = 0; i < 4; ++i)
            stg[i] = *(const s8*)(p + (gi + 128 * i) * 8);
    }

    int buf = 0;
    for (int j = 0; j < h; ++j) {
        // write staged regs -> LDS[ghalf][buf]; K and V use identical layout
        {
            short (*dst)[72] = isV ? lV[ghalf][buf] : lK[ghalf][buf];
            #pragma unroll
            for (int i = 0; i < 4; ++i) {
                int s = gi + 128 * i;
                *(s8*)&dst[s >> 3][(s & 7) * 8] = stg[i];
            }
        }
        __syncthreads();

        // prefetch next tile (hides under compute below)
        if (j + 1 < h) {
            const unsigned short* p = tb + (size_t)((ghalf ? h : 0) + j + 1) * 4096;
            #pragma unroll
            for (int i = 0; i < 4; ++i)
                stg[i] = *(const s8*)(p + (gi + 128 * i) * 8);
        }

        const int kt = (half ? h : 0) + j;
        if (kt <= qt) {                      // half-B pad iter skips
            // S^T = K . Q^T
            f4 st[4];
            #pragma unroll
            for (int kf = 0; kf < 4; ++kf) {
                f4 a = f4{0,0,0,0};
                #pragma unroll
                for (int ks = 0; ks < 4; ++ks) {
                    s4 kfr = *(const s4*)&lK[half][buf][kf * 16 + lr][ks * 16 + 4 * lg];
                    a = MFMA16(kfr, qf[ks], a);
                }
                st[kf] = a;
            }

            const bool diag = (kt == qt);
            const int kbase = kt * 64;
            float smax = -3e38f;
            #pragma unroll
            for (int kf = 0; kf < 4; ++kf) {
                #pragma unroll
                for (int e = 0; e < 4; ++e) {
                    float s = st[kf][e] * 0.125f;
                    if (diag && (kbase + kf * 16 + 4 * lg + e > qrow)) s = -3e38f;
                    st[kf][e] = s;
                    smax = fmaxf(smax, s);
                }
            }
            smax = fmaxf(smax, __shfl_xor(smax, 16));
            smax = fmaxf(smax, __shfl_xor(smax, 32));

            float mnew  = fmaxf(m, smax);
            float scale = __expf(m - mnew);
            float psum  = 0.f;
            s4 pf[4];
            #pragma unroll
            for (int kf = 0; kf < 4; ++kf) {
                f4 p;
                #pragma unroll
                for (int e = 0; e < 4; ++e) { p[e] = __expf(st[kf][e] - mnew); psum += p[e]; }
                s4 pb; pb[0]=f2bf(p[0]); pb[1]=f2bf(p[1]); pb[2]=f2bf(p[2]); pb[3]=f2bf(p[3]);
                pf[kf] = pb;
            }
            psum += __shfl_xor(psum, 16);
            psum += __shfl_xor(psum, 32);
            lsum = lsum * scale + psum;
            m = mnew;
            #pragma unroll
            for (int df = 0; df < 4; ++df) accO[df] *= scale;

            #pragma unroll
            for (int df = 0; df < 4; ++df) {
                #pragma unroll
                for (int kf = 0; kf < 4; ++kf) {
                    s4 vf = *(const s4*)&lV[half][buf][df * 16 + lr][kf * 16 + 4 * lg];
                    accO[df] = MFMA16(vf, pf[kf], accO[df]);
                }
            }
        }
        buf ^= 1;
    }

    // ---- merge halves: B publishes (m, l, accO) via LDS; A combines ----
    __syncthreads();
    float* ex = (float*)&lK[0][0][0][0];     // 256*19 floats = 19.4 KB, fits
    const int idx = (hw * 64 + ln) * 19;
    if (half == 1) {
        ex[idx + 0] = m;
        ex[idx + 1] = lsum;
        #pragma unroll
        for (int df = 0; df < 4; ++df)
            #pragma unroll
            for (int e = 0; e < 4; ++e)
                ex[idx + 2 + df * 4 + e] = accO[df][e];
    }
    __syncthreads();
    if (half == 0) {
        float mB = ex[idx + 0], lB = ex[idx + 1];
        float mx = fmaxf(m, mB);
        float sA = __expf(m - mx), sB = __expf(mB - mx);
        float linv = 1.f / (lsum * sA + lB * sB);
        float* ob = out + ((size_t)b * 2048 + qrow) * 64;
        #pragma unroll
        for (int df = 0; df < 4; ++df) {
            f4 o;
            #pragma unroll
            for (int e = 0; e < 4; ++e)
                o[e] = (accO[df][e] * sA + ex[idx + 2 + df * 4 + e] * sB) * linv;
            *(f4*)(ob + df * 16 + 4 * lg) = o;
        }
    }
}

// ---------------------------------------------------------------------------
extern "C" void kernel_launch(void* const* d_in, const int* in_sizes, int n_in,
                              void* d_out, int out_size, void* d_ws, size_t ws_size,
                              hipStream_t stream) {
    const float* q  = (const float*)d_in[0];
    const float* k  = (const float*)d_in[1];
    const float* v  = (const float*)d_in[2];
    // d_in[3] = causal mask (deterministic tril) — computed analytically
    const float* Wq = (const float*)d_in[4];
    const float* bq = (const float*)d_in[5];
    const float* Wk = (const float*)d_in[6];
    const float* bk = (const float*)d_in[7];
    const float* Wv = (const float*)d_in[8];
    const float* bv = (const float*)d_in[9];

    unsigned short* qp  = (unsigned short*)d_ws;           // [16384][64] bf16
    unsigned short* kp  = qp + (size_t)16384 * 64;
    unsigned short* vpT = kp + (size_t)16384 * 64;         // V^T tiles [b][t][d][key]

    ProjArgs pa;
    pa.X[0] = q;  pa.X[1] = k;  pa.X[2] = v;
    pa.W[0] = Wq; pa.W[1] = Wk; pa.W[2] = Wv;
    pa.b[0] = bq; pa.b[1] = bk; pa.b[2] = bv;
    pa.O[0] = qp; pa.O[1] = kp; pa.O[2] = vpT;
    proj_kernel<<<dim3(256, 3), 256, 0, stream>>>(pa);

    attn_kernel<<<dim3(32, 8), 512, 0, stream>>>(qp, kp, vpT, (float*)d_out);
}

// Round 16
// 75.665 us; speedup vs baseline: 1.1671x; 1.0199x over previous
//
#include <hip/hip_runtime.h>
#include <hip/hip_bf16.h>

typedef short s4 __attribute__((ext_vector_type(4)));
typedef short s8 __attribute__((ext_vector_type(8)));
typedef float f4 __attribute__((ext_vector_type(4)));

#define MFMA16(a, b, c) __builtin_amdgcn_mfma_f32_16x16x16bf16_1k(a, b, c, 0, 0, 0)

__device__ __forceinline__ short f2bf(float f) {
    union { float f; unsigned u; } v; v.f = f;
    unsigned r = v.u + 0x7fffu + ((v.u >> 16) & 1u);   // RNE
    return (short)(r >> 16);
}

// ---------------------------------------------------------------------------
// Kernel 1: projections — R8 structure; ONLY change: V (which==2) epilogue
// now transposes the 64x64 output tile in LDS (lA reused after the final
// barrier) and stores coalesced s8 rows of vpT[b][tile][d][key], replacing
// the 128B-stride scattered 2B stores (64 transactions per wave-store).
// ---------------------------------------------------------------------------
struct ProjArgs {
    const float* X[3];
    const float* W[3];
    const float* b[3];
    unsigned short* O[3];
};

__global__ __launch_bounds__(256) void proj_kernel(ProjArgs args) {
    __shared__ short lA[64][68];   // [row][k]; epilogue (V): [d][key]
    __shared__ short lW[64][68];   // [k][n]

    const int t  = threadIdx.x;
    const int wv = t >> 6, ln = t & 63, lg = ln >> 4, lr = ln & 15;
    const int which = blockIdx.y;

    const float* X = args.X[which] + (size_t)blockIdx.x * 64 * 1024;
    const float* W = args.W[which];

    f4 acc[4] = {f4{0,0,0,0}, f4{0,0,0,0}, f4{0,0,0,0}, f4{0,0,0,0}};

    for (int kk = 0; kk < 1024; kk += 64) {
        #pragma unroll
        for (int i = 0; i < 4; ++i) {
            int f  = t + i * 256;       // float4 index, 0..1023
            int r  = f >> 4;
            int c4 = f & 15;
            f4 a = *(const f4*)(X + (size_t)r * 1024 + kk + c4 * 4);
            f4 w = *(const f4*)(W + (size_t)(kk + r) * 64 + c4 * 4);
            s4 ab; ab[0]=f2bf(a[0]); ab[1]=f2bf(a[1]); ab[2]=f2bf(a[2]); ab[3]=f2bf(a[3]);
            s4 wb; wb[0]=f2bf(w[0]); wb[1]=f2bf(w[1]); wb[2]=f2bf(w[2]); wb[3]=f2bf(w[3]);
            *(s4*)&lA[r][c4 * 4] = ab;
            *(s4*)&lW[r][c4 * 4] = wb;
        }
        __syncthreads();

        #pragma unroll
        for (int ks = 0; ks < 4; ++ks) {
            s4 af = *(const s4*)&lA[wv * 16 + lr][ks * 16 + 4 * lg];
            #pragma unroll
            for (int nf = 0; nf < 4; ++nf) {
                s4 bf;
                #pragma unroll
                for (int e = 0; e < 4; ++e)
                    bf[e] = lW[ks * 16 + 4 * lg + e][nf * 16 + lr];
                acc[nf] = MFMA16(af, bf, acc[nf]);
            }
        }
        __syncthreads();
    }

    // epilogue: + bias, bf16, store
    const float* bias = args.b[which];
    unsigned short* O = args.O[which];
    if (which == 2) {
        // V: write transposed into lA[d][key] (free after last barrier),
        // then coalesced s8 stores of vpT tile rows.
        #pragma unroll
        for (int nf = 0; nf < 4; ++nf) {
            float bs = bias[nf * 16 + lr];
            int d = nf * 16 + lr;
            #pragma unroll
            for (int e = 0; e < 4; ++e) {
                int key = wv * 16 + 4 * lg + e;
                lA[d][key] = (short)f2bf(acc[nf][e] + bs);
            }
        }
        __syncthreads();
        const int grow0 = blockIdx.x * 64;   // 64-aligned -> exactly one tile
        unsigned short* tb = O + (size_t)(grow0 >> 11) * 131072
                               + (size_t)((grow0 & 2047) >> 6) * 4096;
        #pragma unroll
        for (int i = 0; i < 2; ++i) {
            int s = t * 2 + i;               // 0..511
            int d = s >> 3, k8 = s & 7;
            s8 v = *(const s8*)&lA[d][k8 * 8];
            *(s8*)(tb + (size_t)d * 64 + k8 * 8) = v;
        }
    } else {
        #pragma unroll
        for (int nf = 0; nf < 4; ++nf) {
            float bs = bias[nf * 16 + lr];
            int col = nf * 16 + lr;
            #pragma unroll
            for (int e = 0; e < 4; ++e) {
                int r = wv * 16 + 4 * lg + e;
                int grow = blockIdx.x * 64 + r;
                O[(size_t)grow * 64 + col] = (unsigned short)f2bf(acc[nf][e] + bs);
            }
        }
    }
}

// ---------------------------------------------------------------------------
// Kernel 2: causal flash attention — R8 exact (28.7 us timed, measured R9).
// Intra-block 2-way KV-split, 8 waves, double-buffered LDS, one barrier/iter,
// reg prefetch; V staged from vpT with vector s8 writes. grid (32,8), 512 thr.
// ---------------------------------------------------------------------------
__global__ __launch_bounds__(512) void attn_kernel(const unsigned short* __restrict__ qp,
                                                   const unsigned short* __restrict__ kp,
                                                   const unsigned short* __restrict__ vpT,
                                                   float* __restrict__ out) {
    __shared__ short lK[2][2][64][72];   // [half][buf][key][d]
    __shared__ short lV[2][2][64][72];   // [half][buf][d][key]

    const int t    = threadIdx.x;
    const int wave = t >> 6, ln = t & 63, lg = ln >> 4, lr = ln & 15;
    const int half = wave >> 2, hw = wave & 3;
    const int b = blockIdx.y, qt = blockIdx.x;
    const int qrow = qt * 64 + hw * 16 + lr;
    const int h = (qt + 2) >> 1;

    // staging role: 128-thread groups g: 0=K half0, 1=V half0, 2=K half1, 3=V half1
    const int g = t >> 7, gi = t & 127, ghalf = g >> 1;
    const bool isV = (g & 1) != 0;
    const unsigned short* tb = (isV ? vpT : kp) + (size_t)b * 131072;

    const unsigned short* qpb = qp + (size_t)b * 131072;
    s4 qf[4];
    #pragma unroll
    for (int ks = 0; ks < 4; ++ks)
        qf[ks] = *(const s4*)(qpb + (size_t)qrow * 64 + ks * 16 + 4 * lg);

    f4 accO[4] = {f4{0,0,0,0}, f4{0,0,0,0}, f4{0,0,0,0}, f4{0,0,0,0}};
    float m = -3e38f, lsum = 0.f;

    // prologue: prefetch iter-0 tile for this thread's (tensor, half)
    s8 stg[4];
    {
        const unsigned short* p = tb + (size_t)(ghalf ? h : 0) * 4096;
        #pragma unroll
        for (int i = 0; i < 4; ++i)
            stg[i] = *(const s8*)(p + (gi + 128 * i) * 8);
    }

    int buf = 0;
    for (int j = 0; j < h; ++j) {
        // write staged regs -> LDS[ghalf][buf]; K and V use identical layout
        {
            short (*dst)[72] = isV ? lV[ghalf][buf] : lK[ghalf][buf];
            #pragma unroll
            for (int i = 0; i < 4; ++i) {
                int s = gi + 128 * i;
                *(s8*)&dst[s >> 3][(s & 7) * 8] = stg[i];
            }
        }
        __syncthreads();

        // prefetch next tile (hides under compute below)
        if (j + 1 < h) {
            const unsigned short* p = tb + (size_t)((ghalf ? h : 0) + j + 1) * 4096;
            #pragma unroll
            for (int i = 0; i < 4; ++i)
                stg[i] = *(const s8*)(p + (gi + 128 * i) * 8);
        }

        const int kt = (half ? h : 0) + j;
        if (kt <= qt) {                      // half-B pad iter skips
            // S^T = K . Q^T
            f4 st[4];
            #pragma unroll
            for (int kf = 0; kf < 4; ++kf) {
                f4 a = f4{0,0,0,0};
                #pragma unroll
                for (int ks = 0; ks < 4; ++ks) {
                    s4 kfr = *(const s4*)&lK[half][buf][kf * 16 + lr][ks * 16 + 4 * lg];
                    a = MFMA16(kfr, qf[ks], a);
                }
                st[kf] = a;
            }

            const bool diag = (kt == qt);
            const int kbase = kt * 64;
            float smax = -3e38f;
            #pragma unroll
            for (int kf = 0; kf < 4; ++kf) {
                #pragma unroll
                for (int e = 0; e < 4; ++e) {
                    float s = st[kf][e] * 0.125f;
                    if (diag && (kbase + kf * 16 + 4 * lg + e > qrow)) s = -3e38f;
                    st[kf][e] = s;
                    smax = fmaxf(smax, s);
                }
            }
            smax = fmaxf(smax, __shfl_xor(smax, 16));
            smax = fmaxf(smax, __shfl_xor(smax, 32));

            float mnew  = fmaxf(m, smax);
            float scale = __expf(m - mnew);
            float psum  = 0.f;
            s4 pf[4];
            #pragma unroll
            for (int kf = 0; kf < 4; ++kf) {
                f4 p;
                #pragma unroll
                for (int e = 0; e < 4; ++e) { p[e] = __expf(st[kf][e] - mnew); psum += p[e]; }
                s4 pb; pb[0]=f2bf(p[0]); pb[1]=f2bf(p[1]); pb[2]=f2bf(p[2]); pb[3]=f2bf(p[3]);
                pf[kf] = pb;
            }
            psum += __shfl_xor(psum, 16);
            psum += __shfl_xor(psum, 32);
            lsum = lsum * scale + psum;
            m = mnew;
            #pragma unroll
            for (int df = 0; df < 4; ++df) accO[df] *= scale;

            #pragma unroll
            for (int df = 0; df < 4; ++df) {
                #pragma unroll
                for (int kf = 0; kf < 4; ++kf) {
                    s4 vf = *(const s4*)&lV[half][buf][df * 16 + lr][kf * 16 + 4 * lg];
                    accO[df] = MFMA16(vf, pf[kf], accO[df]);
                }
            }
        }
        buf ^= 1;
    }

    // ---- merge halves: B publishes (m, l, accO) via LDS; A combines ----
    __syncthreads();
    float* ex = (float*)&lK[0][0][0][0];     // 256*19 floats = 19.4 KB, fits
    const int idx = (hw * 64 + ln) * 19;
    if (half == 1) {
        ex[idx + 0] = m;
        ex[idx + 1] = lsum;
        #pragma unroll
        for (int df = 0; df < 4; ++df)
            #pragma unroll
            for (int e = 0; e < 4; ++e)
                ex[idx + 2 + df * 4 + e] = accO[df][e];
    }
    __syncthreads();
    if (half == 0) {
        float mB = ex[idx + 0], lB = ex[idx + 1];
        float mx = fmaxf(m, mB);
        float sA = __expf(m - mx), sB = __expf(mB - mx);
        float linv = 1.f / (lsum * sA + lB * sB);
        float* ob = out + ((size_t)b * 2048 + qrow) * 64;
        #pragma unroll
        for (int df = 0; df < 4; ++df) {
            f4 o;
            #pragma unroll
            for (int e = 0; e < 4; ++e)
                o[e] = (accO[df][e] * sA + ex[idx + 2 + df * 4 + e] * sB) * linv;
            *(f4*)(ob + df * 16 + 4 * lg) = o;
        }
    }
}

// ---------------------------------------------------------------------------
extern "C" void kernel_launch(void* const* d_in, const int* in_sizes, int n_in,
                              void* d_out, int out_size, void* d_ws, size_t ws_size,
                              hipStream_t stream) {
    const float* q  = (const float*)d_in[0];
    const float* k  = (const float*)d_in[1];
    const float* v  = (const float*)d_in[2];
    // d_in[3] = causal mask (deterministic tril) — computed analytically
    const float* Wq = (const float*)d_in[4];
    const float* bq = (const float*)d_in[5];
    const float* Wk = (const float*)d_in[6];
    const float* bk = (const float*)d_in[7];
    const float* Wv = (const float*)d_in[8];
    const float* bv = (const float*)d_in[9];

    unsigned short* qp  = (unsigned short*)d_ws;           // [16384][64] bf16
    unsigned short* kp  = qp + (size_t)16384 * 64;
    unsigned short* vpT = kp + (size_t)16384 * 64;         // V^T tiles [b][t][d][key]

    ProjArgs pa;
    pa.X[0] = q;  pa.X[1] = k;  pa.X[2] = v;
    pa.W[0] = Wq; pa.W[1] = Wk; pa.W[2] = Wv;
    pa.b[0] = bq; pa.b[1] = bk; pa.b[2] = bv;
    pa.O[0] = qp; pa.O[1] = kp; pa.O[2] = vpT;
    proj_kernel<<<dim3(256, 3), 256, 0, stream>>>(pa);

    attn_kernel<<<dim3(32, 8), 512, 0, stream>>>(qp, kp, vpT, (float*)d_out);
}

// Round 17
// 64.897 us; speedup vs baseline: 1.3607x; 1.1659x over previous
//
#include <hip/hip_runtime.h>
#include <hip/hip_bf16.h>

typedef short s4 __attribute__((ext_vector_type(4)));
typedef short s8 __attribute__((ext_vector_type(8)));
typedef float f4 __attribute__((ext_vector_type(4)));

#define MFMA16(a, b, c) __builtin_amdgcn_mfma_f32_16x16x16bf16_1k(a, b, c, 0, 0, 0)

__device__ __forceinline__ short f2bf(float f) {
    union { float f; unsigned u; } v; v.f = f;
    unsigned r = v.u + 0x7fffu + ((v.u >> 16) & 1u);   // RNE
    return (short)(r >> 16);
}

// ---------------------------------------------------------------------------
// Kernel 1 v17: projections — R16 structure + register-prefetch double-
// buffered LDS (attn-v8's proven pattern): per k-tile, ONE barrier; tile k+1
// global loads issue right after the barrier and their ~300cy warm-L3 latency
// hides under tile k's MFMA phase (was: vmcnt(0) drain exposed per tile).
// LDS 68 KB -> 2 blocks/CU. V epilogue: transpose-in-LDS + coalesced stores.
// ---------------------------------------------------------------------------
struct ProjArgs {
    const float* X[3];
    const float* W[3];
    const float* b[3];
    unsigned short* O[3];
};

__global__ __launch_bounds__(256) void proj_kernel(ProjArgs args) {
    __shared__ short lA[2][64][68];   // [buf][row][k]; epilogue (V): lA[0]=[d][key]
    __shared__ short lW[2][64][68];   // [buf][k][n]

    const int t  = threadIdx.x;
    const int wv = t >> 6, ln = t & 63, lg = ln >> 4, lr = ln & 15;
    const int which = blockIdx.y;

    const float* X = args.X[which] + (size_t)blockIdx.x * 64 * 1024;
    const float* W = args.W[which];

    f4 acc[4] = {f4{0,0,0,0}, f4{0,0,0,0}, f4{0,0,0,0}, f4{0,0,0,0}};

    // per-thread staging coords (fixed): f = t + i*256 -> r = f>>4, c4 = f&15
    f4 xr[4], wr[4];
#define PROJ_LOAD(kk)                                                         \
    {                                                                         \
        _Pragma("unroll")                                                     \
        for (int i = 0; i < 4; ++i) {                                         \
            int f  = t + i * 256;                                             \
            int r  = f >> 4;                                                  \
            int c4 = f & 15;                                                  \
            xr[i] = *(const f4*)(X + (size_t)r * 1024 + (kk) + c4 * 4);       \
            wr[i] = *(const f4*)(W + (size_t)((kk) + r) * 64 + c4 * 4);       \
        }                                                                     \
    }

    PROJ_LOAD(0)

    int buf = 0;
    for (int j = 0; j < 16; ++j) {
        // convert + write staged regs -> LDS[buf]
        #pragma unroll
        for (int i = 0; i < 4; ++i) {
            int f  = t + i * 256;
            int r  = f >> 4;
            int c4 = f & 15;
            s4 ab; ab[0]=f2bf(xr[i][0]); ab[1]=f2bf(xr[i][1]);
                   ab[2]=f2bf(xr[i][2]); ab[3]=f2bf(xr[i][3]);
            s4 wb; wb[0]=f2bf(wr[i][0]); wb[1]=f2bf(wr[i][1]);
                   wb[2]=f2bf(wr[i][2]); wb[3]=f2bf(wr[i][3]);
            *(s4*)&lA[buf][r][c4 * 4] = ab;
            *(s4*)&lW[buf][r][c4 * 4] = wb;
        }
        __syncthreads();

        // prefetch next tile (latency hides under MFMA below)
        if (j < 15) PROJ_LOAD((j + 1) * 64)

        #pragma unroll
        for (int ks = 0; ks < 4; ++ks) {
            s4 af = *(const s4*)&lA[buf][wv * 16 + lr][ks * 16 + 4 * lg];
            #pragma unroll
            for (int nf = 0; nf < 4; ++nf) {
                s4 bf;
                #pragma unroll
                for (int e = 0; e < 4; ++e)
                    bf[e] = lW[buf][ks * 16 + 4 * lg + e][nf * 16 + lr];
                acc[nf] = MFMA16(af, bf, acc[nf]);
            }
        }
        buf ^= 1;
    }
#undef PROJ_LOAD

    // epilogue: + bias, bf16, store
    const float* bias = args.b[which];
    unsigned short* O = args.O[which];
    if (which == 2) {
        // V: write transposed into lA[0][d][key] (lA[0] last read 2 barriers
        // ago; lA[1] was the final compute buffer), then coalesced s8 stores.
        __syncthreads();
        #pragma unroll
        for (int nf = 0; nf < 4; ++nf) {
            float bs = bias[nf * 16 + lr];
            int d = nf * 16 + lr;
            #pragma unroll
            for (int e = 0; e < 4; ++e) {
                int key = wv * 16 + 4 * lg + e;
                lA[0][d][key] = (short)f2bf(acc[nf][e] + bs);
            }
        }
        __syncthreads();
        const int grow0 = blockIdx.x * 64;   // 64-aligned -> exactly one tile
        unsigned short* tb = O + (size_t)(grow0 >> 11) * 131072
                               + (size_t)((grow0 & 2047) >> 6) * 4096;
        #pragma unroll
        for (int i = 0; i < 2; ++i) {
            int s = t * 2 + i;               // 0..511
            int d = s >> 3, k8 = s & 7;
            s8 v = *(const s8*)&lA[0][d][k8 * 8];
            *(s8*)(tb + (size_t)d * 64 + k8 * 8) = v;
        }
    } else {
        #pragma unroll
        for (int nf = 0; nf < 4; ++nf) {
            float bs = bias[nf * 16 + lr];
            int col = nf * 16 + lr;
            #pragma unroll
            for (int e = 0; e < 4; ++e) {
                int r = wv * 16 + 4 * lg + e;
                int grow = blockIdx.x * 64 + r;
                O[(size_t)grow * 64 + col] = (unsigned short)f2bf(acc[nf][e] + bs);
            }
        }
    }
}

// ---------------------------------------------------------------------------
// Kernel 2: causal flash attention — R8 exact (28.7 us timed, measured R9).
// Intra-block 2-way KV-split, 8 waves, double-buffered LDS, one barrier/iter,
// reg prefetch; V staged from vpT with vector s8 writes. grid (32,8), 512 thr.
// ---------------------------------------------------------------------------
__global__ __launch_bounds__(512) void attn_kernel(const unsigned short* __restrict__ qp,
                                                   const unsigned short* __restrict__ kp,
                                                   const unsigned short* __restrict__ vpT,
                                                   float* __restrict__ out) {
    __shared__ short lK[2][2][64][72];   // [half][buf][key][d]
    __shared__ short lV[2][2][64][72];   // [half][buf][d][key]

    const int t    = threadIdx.x;
    const int wave = t >> 6, ln = t & 63, lg = ln >> 4, lr = ln & 15;
    const int half = wave >> 2, hw = wave & 3;
    const int b = blockIdx.y, qt = blockIdx.x;
    const int qrow = qt * 64 + hw * 16 + lr;
    const int h = (qt + 2) >> 1;

    // staging role: 128-thread groups g: 0=K half0, 1=V half0, 2=K half1, 3=V half1
    const int g = t >> 7, gi = t & 127, ghalf = g >> 1;
    const bool isV = (g & 1) != 0;
    const unsigned short* tb = (isV ? vpT : kp) + (size_t)b * 131072;

    const unsigned short* qpb = qp + (size_t)b * 131072;
    s4 qf[4];
    #pragma unroll
    for (int ks = 0; ks < 4; ++ks)
        qf[ks] = *(const s4*)(qpb + (size_t)qrow * 64 + ks * 16 + 4 * lg);

    f4 accO[4] = {f4{0,0,0,0}, f4{0,0,0,0}, f4{0,0,0,0}, f4{0,0,0,0}};
    float m = -3e38f, lsum = 0.f;

    // prologue: prefetch iter-0 tile for this thread's (tensor, half)
    s8 stg[4];
    {
        const unsigned short* p = tb + (size_t)(ghalf ? h : 0) * 4096;
        #pragma unroll
        for (int i = 0; i < 4; ++i)
            stg[i] = *(const s8*)(p + (gi + 128 * i) * 8);
    }

    int buf = 0;
    for (int j = 0; j < h; ++j) {
        // write staged regs -> LDS[ghalf][buf]; K and V use identical layout
        {
            short (*dst)[72] = isV ? lV[ghalf][buf] : lK[ghalf][buf];
            #pragma unroll
            for (int i = 0; i < 4; ++i) {
                int s = gi + 128 * i;
                *(s8*)&dst[s >> 3][(s & 7) * 8] = stg[i];
            }
        }
        __syncthreads();

        // prefetch next tile (hides under compute below)
        if (j + 1 < h) {
            const unsigned short* p = tb + (size_t)((ghalf ? h : 0) + j + 1) * 4096;
            #pragma unroll
            for (int i = 0; i < 4; ++i)
                stg[i] = *(const s8*)(p + (gi + 128 * i) * 8);
        }

        const int kt = (half ? h : 0) + j;
        if (kt <= qt) {                      // half-B pad iter skips
            // S^T = K . Q^T
            f4 st[4];
            #pragma unroll
            for (int kf = 0; kf < 4; ++kf) {
                f4 a = f4{0,0,0,0};
                #pragma unroll
                for (int ks = 0; ks < 4; ++ks) {
                    s4 kfr = *(const s4*)&lK[half][buf][kf * 16 + lr][ks * 16 + 4 * lg];
                    a = MFMA16(kfr, qf[ks], a);
                }
                st[kf] = a;
            }

            const bool diag = (kt == qt);
            const int kbase = kt * 64;
            float smax = -3e38f;
            #pragma unroll
            for (int kf = 0; kf < 4; ++kf) {
                #pragma unroll
                for (int e = 0; e < 4; ++e) {
                    float s = st[kf][e] * 0.125f;
                    if (diag && (kbase + kf * 16 + 4 * lg + e > qrow)) s = -3e38f;
                    st[kf][e] = s;
                    smax = fmaxf(smax, s);
                }
            }
            smax = fmaxf(smax, __shfl_xor(smax, 16));
            smax = fmaxf(smax, __shfl_xor(smax, 32));

            float mnew  = fmaxf(m, smax);
            float scale = __expf(m - mnew);
            float psum  = 0.f;
            s4 pf[4];
            #pragma unroll
            for (int kf = 0; kf < 4; ++kf) {
                f4 p;
                #pragma unroll
                for (int e = 0; e < 4; ++e) { p[e] = __expf(st[kf][e] - mnew); psum += p[e]; }
                s4 pb; pb[0]=f2bf(p[0]); pb[1]=f2bf(p[1]); pb[2]=f2bf(p[2]); pb[3]=f2bf(p[3]);
                pf[kf] = pb;
            }
            psum += __shfl_xor(psum, 16);
            psum += __shfl_xor(psum, 32);
            lsum = lsum * scale + psum;
            m = mnew;
            #pragma unroll
            for (int df = 0; df < 4; ++df) accO[df] *= scale;

            #pragma unroll
            for (int df = 0; df < 4; ++df) {
                #pragma unroll
                for (int kf = 0; kf < 4; ++kf) {
                    s4 vf = *(const s4*)&lV[half][buf][df * 16 + lr][kf * 16 + 4 * lg];
                    accO[df] = MFMA16(vf, pf[kf], accO[df]);
                }
            }
        }
        buf ^= 1;
    }

    // ---- merge halves: B publishes (m, l, accO) via LDS; A combines ----
    __syncthreads();
    float* ex = (float*)&lK[0][0][0][0];     // 256*19 floats = 19.4 KB, fits
    const int idx = (hw * 64 + ln) * 19;
    if (half == 1) {
        ex[idx + 0] = m;
        ex[idx + 1] = lsum;
        #pragma unroll
        for (int df = 0; df < 4; ++df)
            #pragma unroll
            for (int e = 0; e < 4; ++e)
                ex[idx + 2 + df * 4 + e] = accO[df][e];
    }
    __syncthreads();
    if (half == 0) {
        float mB = ex[idx + 0], lB = ex[idx + 1];
        float mx = fmaxf(m, mB);
        float sA = __expf(m - mx), sB = __expf(mB - mx);
        float linv = 1.f / (lsum * sA + lB * sB);
        float* ob = out + ((size_t)b * 2048 + qrow) * 64;
        #pragma unroll
        for (int df = 0; df < 4; ++df) {
            f4 o;
            #pragma unroll
            for (int e = 0; e < 4; ++e)
                o[e] = (accO[df][e] * sA + ex[idx + 2 + df * 4 + e] * sB) * linv;
            *(f4*)(ob + df * 16 + 4 * lg) = o;
        }
    }
}

// ---------------------------------------------------------------------------
extern "C" void kernel_launch(void* const* d_in, const int* in_sizes, int n_in,
                              void* d_out, int out_size, void* d_ws, size_t ws_size,
                              hipStream_t stream) {
    const float* q  = (const float*)d_in[0];
    const float* k  = (const float*)d_in[1];
    const float* v  = (const float*)d_in[2];
    // d_in[3] = causal mask (deterministic tril) — computed analytically
    const float* Wq = (const float*)d_in[4];
    const float* bq = (const float*)d_in[5];
    const float* Wk = (const float*)d_in[6];
    const float* bk = (const float*)d_in[7];
    const float* Wv = (const float*)d_in[8];
    const float* bv = (const float*)d_in[9];

    unsigned short* qp  = (unsigned short*)d_ws;           // [16384][64] bf16
    unsigned short* kp  = qp + (size_t)16384 * 64;
    unsigned short* vpT = kp + (size_t)16384 * 64;         // V^T tiles [b][t][d][key]

    ProjArgs pa;
    pa.X[0] = q;  pa.X[1] = k;  pa.X[2] = v;
    pa.W[0] = Wq; pa.W[1] = Wk; pa.W[2] = Wv;
    pa.b[0] = bq; pa.b[1] = bk; pa.b[2] = bv;
    pa.O[0] = qp; pa.O[1] = kp; pa.O[2] = vpT;
    proj_kernel<<<dim3(256, 3), 256, 0, stream>>>(pa);

    attn_kernel<<<dim3(32, 8), 512, 0, stream>>>(qp, kp, vpT, (float*)d_out);
}